// Round 2
// baseline (261.512 us; speedup 1.0000x reference)
//
#include <hip/hip_runtime.h>
#include <math.h>

// FAVOR+ linear attention, segment-normalized. fp32 end-to-end (no fp32 MFMA
// on CDNA4; bf16 MFMA deferred until accuracy headroom is measured).
//
// N=8192 rows, D=M=DV=128, B=64 segments (batch_seg sorted => contiguous runs).
//
// ws layout (floats):
//   S      [64*128*128]  outer-product accumulators (zeroed per launch)
//   Ksum   [64*128]      segment sums of Kp        (zeroed)
//   segmax [64]          segment max of rowmax(U_K), clamped >=0 (zeroed)
//   Qp     [8192*128]
//   U_K    [8192*128]
//   h_K    [8192]

#define NROWS 8192
#define DIM   128
#define NSEG  64

#define INV_D4      0.29730177875068026f   // 128^-0.25
#define H_SCALE     0.04419417382415922f   // 1/(2*sqrt(128))
#define INV_SQRT_M  0.08838834764831845f   // 1/sqrt(128)
#define PHI_EPS_F   1e-4f
#define NORM_EPS_F  1e-8f

// ---------------------------------------------------------------------------
// Kernel 1: U = (x * INV_D4) @ omega for Q and K rows.
//   Q rows -> Qp = (exp(U - h - rowmax) + eps)/sqrt(m)   (written directly)
//   K rows -> store U, h; atomicMax positive rowmax into segmax[seg]
// Register blocking: each lane owns 4 rows x 4 cols. Wave handles 8 rows
// (half-wave rg=lane>>5 owns rows {rg, rg+2, rg+4, rg+6}); block = 4 waves
// = 32 rows. Grid = 16384/32 = 512 blocks (first 256 -> Q, rest -> K).
// ---------------------------------------------------------------------------
__global__ __launch_bounds__(256, 2) void k_phi(
    const float* __restrict__ Q, const float* __restrict__ K,
    const float* __restrict__ omega, const int* __restrict__ seg,
    float* __restrict__ Qp, float* __restrict__ UK,
    float* __restrict__ hK, int* __restrict__ segmax)
{
    __shared__ float om[DIM * DIM];      // 64 KB
    __shared__ float xs[4][8][DIM];      // 16 KB, per-wave 8 scaled rows

    const int t = threadIdx.x;
    // stage omega: 4096 float4, 16 per thread, coalesced
    {
        const float4* src = (const float4*)omega;
        float4* dst = (float4*)om;
#pragma unroll
        for (int i = 0; i < 16; ++i) dst[t + i * 256] = src[t + i * 256];
    }

    const int w    = t >> 6;
    const int lane = t & 63;
    const int rg   = lane >> 5;   // row-group within wave
    const int cl   = lane & 31;   // col-lane: owns cols cl*4 .. cl*4+3
    const int rowbase = blockIdx.x * 32 + w * 8;
    const bool isQ = rowbase < NROWS;
    const float* X = isQ ? (Q + (size_t)rowbase * DIM)
                         : (K + (size_t)(rowbase - NROWS) * DIM);

    // stage 8 rows (scaled) + partial sum-of-squares.
    // float4 index i*64+lane belongs to row (i*64+lane)>>5 = 2*i + rg.
    float hpart[4];
    {
        const float4* xg = (const float4*)X;
        float4* xd = (float4*)&xs[w][0][0];
#pragma unroll
        for (int i = 0; i < 4; ++i) {
            float4 v = xg[i * 64 + lane];
            hpart[i] = v.x * v.x + v.y * v.y + v.z * v.z + v.w * v.w;
            float4 sv;
            sv.x = v.x * INV_D4; sv.y = v.y * INV_D4;
            sv.z = v.z * INV_D4; sv.w = v.w * INV_D4;
            xd[i * 64 + lane] = sv;
        }
    }
    // reduce over the 32-lane half-wave -> h for row 2*i+rg
    float hrow[4];
#pragma unroll
    for (int i = 0; i < 4; ++i) {
        float v = hpart[i];
#pragma unroll
        for (int m = 1; m < 32; m <<= 1) v += __shfl_xor(v, m, 64);
        hrow[i] = v * H_SCALE;
    }
    __syncthreads();

    float4 acc[4];
#pragma unroll
    for (int i = 0; i < 4; ++i) acc[i] = make_float4(0.f, 0.f, 0.f, 0.f);

#pragma unroll 4
    for (int d = 0; d < DIM; d += 4) {
        const float4 o0 = *(const float4*)&om[(d + 0) * DIM + cl * 4];
        const float4 o1 = *(const float4*)&om[(d + 1) * DIM + cl * 4];
        const float4 o2 = *(const float4*)&om[(d + 2) * DIM + cl * 4];
        const float4 o3 = *(const float4*)&om[(d + 3) * DIM + cl * 4];
#pragma unroll
        for (int i = 0; i < 4; ++i) {
            const float4 xv = *(const float4*)&xs[w][2 * i + rg][d];
            acc[i].x = fmaf(xv.x, o0.x, fmaf(xv.y, o1.x, fmaf(xv.z, o2.x, fmaf(xv.w, o3.x, acc[i].x))));
            acc[i].y = fmaf(xv.x, o0.y, fmaf(xv.y, o1.y, fmaf(xv.z, o2.y, fmaf(xv.w, o3.y, acc[i].y))));
            acc[i].z = fmaf(xv.x, o0.z, fmaf(xv.y, o1.z, fmaf(xv.z, o2.z, fmaf(xv.w, o3.z, acc[i].z))));
            acc[i].w = fmaf(xv.x, o0.w, fmaf(xv.y, o1.w, fmaf(xv.z, o2.w, fmaf(xv.w, o3.w, acc[i].w))));
        }
    }

#pragma unroll
    for (int i = 0; i < 4; ++i) {
        const int row = rowbase + 2 * i + rg;
        const float4 a = acc[i];
        float mx = fmaxf(fmaxf(a.x, a.y), fmaxf(a.z, a.w));
#pragma unroll
        for (int m = 1; m < 32; m <<= 1) mx = fmaxf(mx, __shfl_xor(mx, m, 64));
        if (isQ) {
            const float b = hrow[i] + mx;
            float4 o;
            o.x = (__expf(a.x - b) + PHI_EPS_F) * INV_SQRT_M;
            o.y = (__expf(a.y - b) + PHI_EPS_F) * INV_SQRT_M;
            o.z = (__expf(a.z - b) + PHI_EPS_F) * INV_SQRT_M;
            o.w = (__expf(a.w - b) + PHI_EPS_F) * INV_SQRT_M;
            *(float4*)&Qp[(size_t)row * DIM + cl * 4] = o;
        } else {
            const int krow = row - NROWS;
            *(float4*)&UK[(size_t)krow * DIM + cl * 4] = a;
            if (cl == 0) {
                hK[krow] = hrow[i];
                if (mx > 0.0f)   // zero-init implements the max(.,0) clamp;
                                 // int compare == float compare for positives
                    atomicMax(&segmax[seg[krow]], __float_as_int(mx));
            }
        }
    }
}

// ---------------------------------------------------------------------------
// Kernel 2: per segment, S[b] += Kp^T V (outer products), Ksum[b] += Kp.
// Grid = 64 segments x 4 splits. 8x8 register tile per thread, 4 rows staged
// per sync. Kp computed on the fly from U_K/h_K/segmax. atomicAdd at end.
// ---------------------------------------------------------------------------
__global__ __launch_bounds__(256, 2) void k_accum(
    const float* __restrict__ UK, const float* __restrict__ hK,
    const float* __restrict__ V, const int* __restrict__ seg,
    const float* __restrict__ segmax,
    float* __restrict__ S, float* __restrict__ Ksum)
{
    __shared__ float kp[4][DIM];
    __shared__ float vv[4][DIM];

    const int t = threadIdx.x;
    const int sid  = blockIdx.x >> 2;
    const int part = blockIdx.x & 3;

    // binary search segment bounds (batch_seg sorted); all threads redundant
    int start, end;
    {
        int a = 0, b = NROWS;
        while (a < b) { int m = (a + b) >> 1; if (seg[m] < sid) a = m + 1; else b = m; }
        start = a;
        b = NROWS;
        while (a < b) { int m = (a + b) >> 1; if (seg[m] < sid + 1) a = m + 1; else b = m; }
        end = a;
    }
    const int cnt = end - start;
    const int per = (cnt + 3) >> 2;
    const int s0 = start + part * per;
    const int s1 = min(s0 + per, end);

    const float smax = segmax[sid];
    const int d  = t & 127;       // fixed dim for staging & Ksum
    const int rp = t >> 7;        // 0/1: which of each row-pair this thread stages
    const int tm = (t >> 4) * 8;  // m-tile base
    const int tv = (t & 15) * 8;  // dv-tile base

    float accS[8][8];
#pragma unroll
    for (int a = 0; a < 8; ++a)
#pragma unroll
        for (int b = 0; b < 8; ++b) accS[a][b] = 0.f;
    float ksl = 0.f;

    for (int j = s0; j < s1; j += 4) {
#pragma unroll
        for (int rr = 0; rr < 2; ++rr) {
            const int row = j + rp + rr * 2;
            float kpv = 0.f, vvv = 0.f;
            if (row < s1) {
                const float u = UK[(size_t)row * DIM + d];
                const float h = hK[row];
                kpv = (__expf(u - h - smax) + PHI_EPS_F) * INV_SQRT_M;
                vvv = V[(size_t)row * DIM + d];
            }
            kp[rp + rr * 2][d] = kpv;
            vv[rp + rr * 2][d] = vvv;
            ksl += kpv;
        }
        __syncthreads();
#pragma unroll
        for (int r = 0; r < 4; ++r) {
            const float4 ka = *(const float4*)&kp[r][tm];
            const float4 kb = *(const float4*)&kp[r][tm + 4];
            const float4 va = *(const float4*)&vv[r][tv];
            const float4 vb = *(const float4*)&vv[r][tv + 4];
            const float kk[8] = {ka.x, ka.y, ka.z, ka.w, kb.x, kb.y, kb.z, kb.w};
            const float vr[8] = {va.x, va.y, va.z, va.w, vb.x, vb.y, vb.z, vb.w};
#pragma unroll
            for (int a = 0; a < 8; ++a)
#pragma unroll
                for (int b = 0; b < 8; ++b)
                    accS[a][b] = fmaf(kk[a], vr[b], accS[a][b]);
        }
        __syncthreads();
    }

    float* Sseg = S + (size_t)sid * DIM * DIM;
#pragma unroll
    for (int a = 0; a < 8; ++a)
#pragma unroll
        for (int b = 0; b < 8; ++b)
            atomicAdd(&Sseg[(tm + a) * DIM + tv + b], accS[a][b]);
    atomicAdd(&Ksum[sid * DIM + d], ksl);
}

// ---------------------------------------------------------------------------
// Kernel 3: out_i = (Qp_i @ S[seg]) / (Qp_i . Ksum[seg] + eps).
// Block = 256 threads, 32 consecutive rows; S[seg] staged in LDS (re-staged
// at segment boundaries). Each lane: 4 cols x 2 rows (half-wave row split).
// ---------------------------------------------------------------------------
__global__ __launch_bounds__(256, 2) void k_out(
    const float* __restrict__ Qp, const float* __restrict__ S,
    const float* __restrict__ Ksum, const int* __restrict__ seg,
    float* __restrict__ out)
{
    __shared__ float Sl[DIM * DIM];  // 64 KB
    __shared__ float Ks[DIM];
    __shared__ float qb[4][4 * DIM]; // 4 Qp rows per wave

    const int t = threadIdx.x;
    const int w = t >> 6, lane = t & 63;
    const int rg = lane >> 5, cl = lane & 31;
    const int base = blockIdx.x * 32;
    const int bend = base + 32;

    int i = base;
    while (i < bend) {
        const int sid = seg[i];
        int e = i + 1;
        while (e < bend && seg[e] == sid) ++e;

        __syncthreads();  // previous segment's Sl reads must complete
        {
            const float4* src = (const float4*)(S + (size_t)sid * DIM * DIM);
            float4* dst = (float4*)Sl;
#pragma unroll
            for (int q = 0; q < 16; ++q) dst[t + q * 256] = src[t + q * 256];
            if (t < DIM) Ks[t] = Ksum[sid * DIM + t];
        }
        __syncthreads();

        for (int r0 = i + w * 4; r0 < e; r0 += 16) {
            // stage 4 Qp rows (contiguous). Reads may run up to 3 rows past e
            // (different segment, discarded) — clamp only the global OOB edge.
            {
                float2* dst = (float2*)&qb[w][0];
#pragma unroll
                for (int q = 0; q < 4; ++q) {
                    const int idx = q * 64 + lane;             // row r0+(idx>>6)
                    const int grow = min(r0 + (idx >> 6), NROWS - 1);
                    dst[idx] = ((const float2*)(Qp + (size_t)grow * DIM))[idx & 63];
                }
            }
            const float* qA = &qb[w][(rg * 2 + 0) * DIM];
            const float* qB = &qb[w][(rg * 2 + 1) * DIM];
            float4 accA = make_float4(0.f, 0.f, 0.f, 0.f);
            float4 accB = make_float4(0.f, 0.f, 0.f, 0.f);
            float nA = 0.f, nB = 0.f;

#pragma unroll 4
            for (int m = 0; m < DIM; m += 4) {
                const float4 qa4 = *(const float4*)&qA[m];
                const float4 qb4 = *(const float4*)&qB[m];
                const float4 ks4 = *(const float4*)&Ks[m];
                const float qav[4] = {qa4.x, qa4.y, qa4.z, qa4.w};
                const float qbv[4] = {qb4.x, qb4.y, qb4.z, qb4.w};
                const float ksv[4] = {ks4.x, ks4.y, ks4.z, ks4.w};
#pragma unroll
                for (int k = 0; k < 4; ++k) {
                    const float4 s4 = *(const float4*)&Sl[(m + k) * DIM + cl * 4];
                    accA.x = fmaf(qav[k], s4.x, accA.x);
                    accA.y = fmaf(qav[k], s4.y, accA.y);
                    accA.z = fmaf(qav[k], s4.z, accA.z);
                    accA.w = fmaf(qav[k], s4.w, accA.w);
                    accB.x = fmaf(qbv[k], s4.x, accB.x);
                    accB.y = fmaf(qbv[k], s4.y, accB.y);
                    accB.z = fmaf(qbv[k], s4.z, accB.z);
                    accB.w = fmaf(qbv[k], s4.w, accB.w);
                    nA = fmaf(qav[k], ksv[k], nA);
                    nB = fmaf(qbv[k], ksv[k], nB);
                }
            }

            const int rA = r0 + rg * 2, rB = rA + 1;
            if (rA < e) {
                const float inv = 1.0f / (nA + NORM_EPS_F);
                float4 o; o.x = accA.x * inv; o.y = accA.y * inv;
                o.z = accA.z * inv; o.w = accA.w * inv;
                *(float4*)&out[(size_t)rA * DIM + cl * 4] = o;
            }
            if (rB < e) {
                const float inv = 1.0f / (nB + NORM_EPS_F);
                float4 o; o.x = accB.x * inv; o.y = accB.y * inv;
                o.z = accB.z * inv; o.w = accB.w * inv;
                *(float4*)&out[(size_t)rB * DIM + cl * 4] = o;
            }
        }
        i = e;
    }
}

// ---------------------------------------------------------------------------
extern "C" void kernel_launch(void* const* d_in, const int* in_sizes, int n_in,
                              void* d_out, int out_size, void* d_ws, size_t ws_size,
                              hipStream_t stream)
{
    const float* Q     = (const float*)d_in[0];
    const float* K     = (const float*)d_in[1];
    const float* V     = (const float*)d_in[2];
    const float* omega = (const float*)d_in[3];
    const int*   seg   = (const int*)d_in[4];
    float* out = (float*)d_out;

    float* ws     = (float*)d_ws;
    float* S      = ws;
    float* Ksum   = S + (size_t)NSEG * DIM * DIM;
    float* segmax = Ksum + NSEG * DIM;
    float* Qp     = segmax + NSEG;
    float* UK     = Qp + (size_t)NROWS * DIM;
    float* hK     = UK + (size_t)NROWS * DIM;

    // zero the accumulators (ws is poisoned 0xAA before every timed call)
    hipMemsetAsync(S, 0, (size_t)(NSEG * DIM * DIM + NSEG * DIM + NSEG) * sizeof(float), stream);

    hipLaunchKernelGGL(k_phi, dim3(512), dim3(256), 0, stream,
                       Q, K, omega, seg, Qp, UK, hK, (int*)segmax);
    hipLaunchKernelGGL(k_accum, dim3(256), dim3(256), 0, stream,
                       UK, hK, V, seg, segmax, S, Ksum);
    hipLaunchKernelGGL(k_out, dim3(256), dim3(256), 0, stream,
                       Qp, S, Ksum, seg, out);
}

// Round 6
// 153.480 us; speedup vs baseline: 1.7039x; 1.7039x over previous
//
#include <hip/hip_runtime.h>
#include <math.h>

// FAVOR+ linear attention, segment-normalized. fp32 end-to-end.
// N=8192 rows, D=M=DV=128, B=64 segments (batch_seg sorted => contiguous runs).
//
// ws layout (floats):
//   S      [64*128*128]  per-segment Kp^T V   (fully written by k_accum, no zeroing)
//   Ksum   [64*128]      segment sums of Kp   (fully written by k_accum)
//   segmax [64]          segment max of rowmax(U_K), clamped >=0 (memset to 0)
//   Qp     [8192*128]
//   U_K    [8192*128]
//   h_K    [8192]

#define NROWS 8192
#define DIM   128
#define NSEG  64

#define INV_D4      0.29730177875068026f   // 128^-0.25
#define H_SCALE     0.04419417382415922f   // 1/(2*sqrt(128))
#define INV_SQRT_M  0.08838834764831845f   // 1/sqrt(128)
#define PHI_EPS_F   1e-4f
#define NORM_EPS_F  1e-8f

// ---------------------------------------------------------------------------
// Kernel 1: U = (x * INV_D4) @ omega for Q and K rows.
//   Q rows -> Qp = (exp(U - h - rowmax) + eps)/sqrt(m)   (written directly)
//   K rows -> store U, h; atomicMax positive rowmax into segmax[seg]
// ---------------------------------------------------------------------------
__global__ __launch_bounds__(256, 2) void k_phi(
    const float* __restrict__ Q, const float* __restrict__ K,
    const float* __restrict__ omega, const int* __restrict__ seg,
    float* __restrict__ Qp, float* __restrict__ UK,
    float* __restrict__ hK, int* __restrict__ segmax)
{
    __shared__ float om[DIM * DIM];      // 64 KB
    __shared__ float xs[4][8][DIM];      // 16 KB, per-wave 8 scaled rows

    const int t = threadIdx.x;
    {
        const float4* src = (const float4*)omega;
        float4* dst = (float4*)om;
#pragma unroll
        for (int i = 0; i < 16; ++i) dst[t + i * 256] = src[t + i * 256];
    }

    const int w    = t >> 6;
    const int lane = t & 63;
    const int rg   = lane >> 5;   // row-group within wave
    const int cl   = lane & 31;   // col-lane: owns cols cl*4 .. cl*4+3
    const int rowbase = blockIdx.x * 32 + w * 8;
    const bool isQ = rowbase < NROWS;
    const float* X = isQ ? (Q + (size_t)rowbase * DIM)
                         : (K + (size_t)(rowbase - NROWS) * DIM);

    float hpart[4];
    {
        const float4* xg = (const float4*)X;
        float4* xd = (float4*)&xs[w][0][0];
#pragma unroll
        for (int i = 0; i < 4; ++i) {
            float4 v = xg[i * 64 + lane];
            hpart[i] = v.x * v.x + v.y * v.y + v.z * v.z + v.w * v.w;
            float4 sv;
            sv.x = v.x * INV_D4; sv.y = v.y * INV_D4;
            sv.z = v.z * INV_D4; sv.w = v.w * INV_D4;
            xd[i * 64 + lane] = sv;
        }
    }
    float hrow[4];
#pragma unroll
    for (int i = 0; i < 4; ++i) {
        float v = hpart[i];
#pragma unroll
        for (int m = 1; m < 32; m <<= 1) v += __shfl_xor(v, m, 64);
        hrow[i] = v * H_SCALE;
    }
    __syncthreads();

    float4 acc[4];
#pragma unroll
    for (int i = 0; i < 4; ++i) acc[i] = make_float4(0.f, 0.f, 0.f, 0.f);

#pragma unroll 4
    for (int d = 0; d < DIM; d += 4) {
        const float4 o0 = *(const float4*)&om[(d + 0) * DIM + cl * 4];
        const float4 o1 = *(const float4*)&om[(d + 1) * DIM + cl * 4];
        const float4 o2 = *(const float4*)&om[(d + 2) * DIM + cl * 4];
        const float4 o3 = *(const float4*)&om[(d + 3) * DIM + cl * 4];
#pragma unroll
        for (int i = 0; i < 4; ++i) {
            const float4 xv = *(const float4*)&xs[w][2 * i + rg][d];
            acc[i].x = fmaf(xv.x, o0.x, fmaf(xv.y, o1.x, fmaf(xv.z, o2.x, fmaf(xv.w, o3.x, acc[i].x))));
            acc[i].y = fmaf(xv.x, o0.y, fmaf(xv.y, o1.y, fmaf(xv.z, o2.y, fmaf(xv.w, o3.y, acc[i].y))));
            acc[i].z = fmaf(xv.x, o0.z, fmaf(xv.y, o1.z, fmaf(xv.z, o2.z, fmaf(xv.w, o3.z, acc[i].z))));
            acc[i].w = fmaf(xv.x, o0.w, fmaf(xv.y, o1.w, fmaf(xv.z, o2.w, fmaf(xv.w, o3.w, acc[i].w))));
        }
    }

#pragma unroll
    for (int i = 0; i < 4; ++i) {
        const int row = rowbase + 2 * i + rg;
        const float4 a = acc[i];
        float mx = fmaxf(fmaxf(a.x, a.y), fmaxf(a.z, a.w));
#pragma unroll
        for (int m = 1; m < 32; m <<= 1) mx = fmaxf(mx, __shfl_xor(mx, m, 64));
        if (isQ) {
            const float b = hrow[i] + mx;
            float4 o;
            o.x = (__expf(a.x - b) + PHI_EPS_F) * INV_SQRT_M;
            o.y = (__expf(a.y - b) + PHI_EPS_F) * INV_SQRT_M;
            o.z = (__expf(a.z - b) + PHI_EPS_F) * INV_SQRT_M;
            o.w = (__expf(a.w - b) + PHI_EPS_F) * INV_SQRT_M;
            *(float4*)&Qp[(size_t)row * DIM + cl * 4] = o;
        } else {
            const int krow = row - NROWS;
            *(float4*)&UK[(size_t)krow * DIM + cl * 4] = a;
            if (cl == 0) {
                hK[krow] = hrow[i];
                if (mx > 0.0f)   // zero-init implements the max(.,0) clamp;
                                 // int compare == float compare for positives
                    atomicMax(&segmax[seg[krow]], __float_as_int(mx));
            }
        }
    }
}

// ---------------------------------------------------------------------------
// Kernel 2 (v2): per (segment, 32x32 tile) block: S_tile = Kp(:,tm)^T V(:,tv)
// over ALL rows of the segment. Grid = 64 seg * 16 tiles = 1024 blocks,
// 4 blocks/CU, direct stores (NO atomics). Ksum computed by tv==0 blocks via
// register partials + LDS column reduce. Kp from UK/hK/segmax on the fly.
// ---------------------------------------------------------------------------
__global__ __launch_bounds__(256, 4) void k_accum(
    const float* __restrict__ UK, const float* __restrict__ hK,
    const float* __restrict__ V, const int* __restrict__ seg,
    const float* __restrict__ segmax,
    float* __restrict__ S, float* __restrict__ Ksum)
{
    __shared__ float kp[32][32];
    __shared__ float vv[32][32];

    const int t = threadIdx.x;
    const int sid  = blockIdx.x >> 4;
    const int tile = blockIdx.x & 15;
    const int tm = (tile >> 2) * 32;   // phi-feature (m) offset
    const int tv = (tile & 3) * 32;    // dv offset

    // binary search segment bounds (batch_seg sorted); all threads redundant
    int start, end;
    {
        int a = 0, b = NROWS;
        while (a < b) { int m = (a + b) >> 1; if (seg[m] < sid) a = m + 1; else b = m; }
        start = a;
        b = NROWS;
        while (a < b) { int m = (a + b) >> 1; if (seg[m] < sid + 1) a = m + 1; else b = m; }
        end = a;
    }

    const float smax = segmax[sid];
    const int rs = t >> 3;        // staging row slot 0..31
    const int cs = (t & 7) * 4;   // staging col offset
    const int ty = t >> 4;        // compute: m-dir 0..15
    const int tx = t & 15;        // compute: dv-dir 0..15

    float a00 = 0.f, a01 = 0.f, a10 = 0.f, a11 = 0.f;
    float4 ksl = make_float4(0.f, 0.f, 0.f, 0.f);

    for (int j = start; j < end; j += 32) {
        const int row = j + rs;
        float4 kpv = make_float4(0.f, 0.f, 0.f, 0.f);
        float4 vvv = make_float4(0.f, 0.f, 0.f, 0.f);
        if (row < end) {
            const float4 u = *(const float4*)&UK[(size_t)row * DIM + tm + cs];
            const float h = hK[row] + smax;
            kpv.x = (__expf(u.x - h) + PHI_EPS_F) * INV_SQRT_M;
            kpv.y = (__expf(u.y - h) + PHI_EPS_F) * INV_SQRT_M;
            kpv.z = (__expf(u.z - h) + PHI_EPS_F) * INV_SQRT_M;
            kpv.w = (__expf(u.w - h) + PHI_EPS_F) * INV_SQRT_M;
            vvv = *(const float4*)&V[(size_t)row * DIM + tv + cs];
        }
        __syncthreads();   // previous iteration's LDS reads must be done
        *(float4*)&kp[rs][cs] = kpv;
        *(float4*)&vv[rs][cs] = vvv;
        ksl.x += kpv.x; ksl.y += kpv.y; ksl.z += kpv.z; ksl.w += kpv.w;
        __syncthreads();
#pragma unroll
        for (int k = 0; k < 32; ++k) {
            const float2 ka = *(const float2*)&kp[k][ty * 2];
            const float2 vb = *(const float2*)&vv[k][tx * 2];
            a00 = fmaf(ka.x, vb.x, a00);
            a01 = fmaf(ka.x, vb.y, a01);
            a10 = fmaf(ka.y, vb.x, a10);
            a11 = fmaf(ka.y, vb.y, a11);
        }
    }

    // direct store of the 32x32 tile (2 rows x float2 per thread)
    float* Sseg = S + (size_t)sid * DIM * DIM;
    {
        float2 r0; r0.x = a00; r0.y = a01;
        float2 r1; r1.x = a10; r1.y = a11;
        *(float2*)&Sseg[(tm + 2 * ty + 0) * DIM + tv + 2 * tx] = r0;
        *(float2*)&Sseg[(tm + 2 * ty + 1) * DIM + tv + 2 * tx] = r1;
    }

    // Ksum: column-reduce the per-rowslot partials (only tv==0 stores)
    __syncthreads();
    *(float4*)&kp[rs][cs] = ksl;
    __syncthreads();
    if (tv == 0 && t < 32) {
        float s = 0.f;
#pragma unroll
        for (int r = 0; r < 32; ++r) s += kp[r][t];
        Ksum[sid * DIM + tm + t] = s;
    }
}

// ---------------------------------------------------------------------------
// Kernel 3: out_i = (Qp_i @ S[seg]) / (Qp_i . Ksum[seg] + eps).
// Block = 256 threads, 16 consecutive rows (grid 512 => 2 blocks/CU);
// S[seg] staged in LDS, re-staged at segment boundaries.
// ---------------------------------------------------------------------------
__global__ __launch_bounds__(256, 2) void k_out(
    const float* __restrict__ Qp, const float* __restrict__ S,
    const float* __restrict__ Ksum, const int* __restrict__ seg,
    float* __restrict__ out)
{
    __shared__ float Sl[DIM * DIM];  // 64 KB
    __shared__ float Ks[DIM];
    __shared__ float qb[4][4 * DIM]; // 4 Qp rows per wave

    const int t = threadIdx.x;
    const int w = t >> 6, lane = t & 63;
    const int rg = lane >> 5, cl = lane & 31;
    const int base = blockIdx.x * 16;
    const int bend = base + 16;

    int i = base;
    while (i < bend) {
        const int sid = seg[i];
        int e = i + 1;
        while (e < bend && seg[e] == sid) ++e;

        __syncthreads();  // previous segment's Sl reads must complete
        {
            const float4* src = (const float4*)(S + (size_t)sid * DIM * DIM);
            float4* dst = (float4*)Sl;
#pragma unroll
            for (int q = 0; q < 16; ++q) dst[t + q * 256] = src[t + q * 256];
            if (t < DIM) Ks[t] = Ksum[sid * DIM + t];
        }
        __syncthreads();

        for (int r0 = i + w * 4; r0 < e; r0 += 16) {
            {
                float2* dst = (float2*)&qb[w][0];
#pragma unroll
                for (int q = 0; q < 4; ++q) {
                    const int idx = q * 64 + lane;             // row r0+(idx>>6)
                    const int grow = min(r0 + (idx >> 6), NROWS - 1);
                    dst[idx] = ((const float2*)(Qp + (size_t)grow * DIM))[idx & 63];
                }
            }
            const float* qA = &qb[w][(rg * 2 + 0) * DIM];
            const float* qB = &qb[w][(rg * 2 + 1) * DIM];
            float4 accA = make_float4(0.f, 0.f, 0.f, 0.f);
            float4 accB = make_float4(0.f, 0.f, 0.f, 0.f);
            float nA = 0.f, nB = 0.f;

#pragma unroll 4
            for (int m = 0; m < DIM; m += 4) {
                const float4 qa4 = *(const float4*)&qA[m];
                const float4 qb4 = *(const float4*)&qB[m];
                const float4 ks4 = *(const float4*)&Ks[m];
                const float qav[4] = {qa4.x, qa4.y, qa4.z, qa4.w};
                const float qbv[4] = {qb4.x, qb4.y, qb4.z, qb4.w};
                const float ksv[4] = {ks4.x, ks4.y, ks4.z, ks4.w};
#pragma unroll
                for (int k = 0; k < 4; ++k) {
                    const float4 s4 = *(const float4*)&Sl[(m + k) * DIM + cl * 4];
                    accA.x = fmaf(qav[k], s4.x, accA.x);
                    accA.y = fmaf(qav[k], s4.y, accA.y);
                    accA.z = fmaf(qav[k], s4.z, accA.z);
                    accA.w = fmaf(qav[k], s4.w, accA.w);
                    accB.x = fmaf(qbv[k], s4.x, accB.x);
                    accB.y = fmaf(qbv[k], s4.y, accB.y);
                    accB.z = fmaf(qbv[k], s4.z, accB.z);
                    accB.w = fmaf(qbv[k], s4.w, accB.w);
                    nA = fmaf(qav[k], ksv[k], nA);
                    nB = fmaf(qbv[k], ksv[k], nB);
                }
            }

            const int rA = r0 + rg * 2, rB = rA + 1;
            if (rA < e) {
                const float inv = 1.0f / (nA + NORM_EPS_F);
                float4 o; o.x = accA.x * inv; o.y = accA.y * inv;
                o.z = accA.z * inv; o.w = accA.w * inv;
                *(float4*)&out[(size_t)rA * DIM + cl * 4] = o;
            }
            if (rB < e) {
                const float inv = 1.0f / (nB + NORM_EPS_F);
                float4 o; o.x = accB.x * inv; o.y = accB.y * inv;
                o.z = accB.z * inv; o.w = accB.w * inv;
                *(float4*)&out[(size_t)rB * DIM + cl * 4] = o;
            }
        }
        i = e;
    }
}

// ---------------------------------------------------------------------------
extern "C" void kernel_launch(void* const* d_in, const int* in_sizes, int n_in,
                              void* d_out, int out_size, void* d_ws, size_t ws_size,
                              hipStream_t stream)
{
    const float* Q     = (const float*)d_in[0];
    const float* K     = (const float*)d_in[1];
    const float* V     = (const float*)d_in[2];
    const float* omega = (const float*)d_in[3];
    const int*   seg   = (const int*)d_in[4];
    float* out = (float*)d_out;

    float* ws     = (float*)d_ws;
    float* S      = ws;
    float* Ksum   = S + (size_t)NSEG * DIM * DIM;
    float* segmax = Ksum + NSEG * DIM;
    float* Qp     = segmax + NSEG;
    float* UK     = Qp + (size_t)NROWS * DIM;
    float* hK     = UK + (size_t)NROWS * DIM;

    // S and Ksum are now fully written by k_accum; only segmax needs zeroing.
    hipMemsetAsync(segmax, 0, NSEG * sizeof(float), stream);

    hipLaunchKernelGGL(k_phi, dim3(512), dim3(256), 0, stream,
                       Q, K, omega, seg, Qp, UK, hK, (int*)segmax);
    hipLaunchKernelGGL(k_accum, dim3(NSEG * 16), dim3(256), 0, stream,
                       UK, hK, V, seg, segmax, S, Ksum);
    hipLaunchKernelGGL(k_out, dim3(512), dim3(256), 0, stream,
                       Qp, S, Ksum, seg, out);
}